// Round 3
// baseline (539.347 us; speedup 1.0000x reference)
//
#include <hip/hip_runtime.h>

typedef __attribute__((ext_vector_type(8))) short short8;
typedef __attribute__((ext_vector_type(4))) short short4v;
typedef __attribute__((ext_vector_type(4))) float floatx4;

// ---------- bf16 helpers (manual, RNE) ----------
__device__ __forceinline__ unsigned short f2bf(float f) {
    unsigned u = __float_as_uint(f);
    u = u + 0x7fffu + ((u >> 16) & 1u);
    return (unsigned short)(u >> 16);
}
__device__ __forceinline__ float bf2f(short s) {
    return __uint_as_float(((unsigned)(unsigned short)s) << 16);
}

// ---------- async global->LDS, 16B per lane ----------
__device__ __forceinline__ void gl_lds16(const void* g, void* l) {
    __builtin_amdgcn_global_load_lds((const __attribute__((address_space(1))) void*)g,
                                     (__attribute__((address_space(3))) void*)l, 16, 0, 0);
}

// ---------- K0: fused convert x->bf16 + partial column sums over N ----------
__global__ __launch_bounds__(256) void convmean_kernel(const float* __restrict__ x,
                                                       short* __restrict__ xb,
                                                       float* __restrict__ part) {
    int bid = blockIdx.x;
    int b = bid >> 6, nch = bid & 63;
    int tid = threadIdx.x;
    size_t base = ((size_t)b * 2048 + nch * 32) * 1024;
    float s0 = 0.f, s1 = 0.f, s2 = 0.f, s3 = 0.f;
    int c0 = tid * 4;
    for (int r = 0; r < 32; r++) {
        const float* rp = x + base + (size_t)r * 1024 + c0;
        float4 v = *(const float4*)rp;
        s0 += v.x; s1 += v.y; s2 += v.z; s3 += v.w;
        short4v o;
        o[0] = (short)f2bf(v.x); o[1] = (short)f2bf(v.y);
        o[2] = (short)f2bf(v.z); o[3] = (short)f2bf(v.w);
        *(short4v*)(xb + base + (size_t)r * 1024 + c0) = o;
    }
    float* pp = part + ((size_t)b * 64 + nch) * 1024 + c0;
    float4 ps; ps.x = s0; ps.y = s1; ps.z = s2; ps.w = s3;
    *(float4*)pp = ps;
}

// ---------- K1: fused transpose+convert, with q/k interleave permutation ----------
// qkvT row for original qkv_w column j:  q_j -> 2j,  k_j -> 2j+1,  v_j -> unchanged
__global__ __launch_bounds__(256) void transpose_conv_kernel(const float* __restrict__ w_qkv,
                                                             short* __restrict__ qkvT,
                                                             const float* __restrict__ w_proj,
                                                             short* __restrict__ projT) {
    __shared__ float t[64][65];
    int bx = blockIdx.x;
    const float* in; short* out; int C; bool is_qkv;
    int c0, r0 = blockIdx.y * 64;
    if (bx < 48) { in = w_qkv; out = qkvT; C = 3072; c0 = bx * 64; is_qkv = true; }
    else         { in = w_proj; out = projT; C = 1024; c0 = (bx - 48) * 64; is_qkv = false; }
    int tid = threadIdx.x;
#pragma unroll
    for (int l = 0; l < 16; l++) {
        int idx = l * 256 + tid;
        int rr = idx >> 6, cc = idx & 63;
        t[rr][cc] = in[(size_t)(r0 + rr) * C + c0 + cc];
    }
    __syncthreads();
#pragma unroll
    for (int l = 0; l < 16; l++) {
        int idx = l * 256 + tid;
        int rr = idx >> 6, cc = idx & 63;
        int ro = c0 + rr;
        int rnew = ro;
        if (is_qkv) {
            if (ro < 1024) rnew = 2 * ro;
            else if (ro < 2048) rnew = 2 * (ro - 1024) + 1;
        }
        out[(size_t)rnew * 1024 + r0 + cc] = (short)f2bf(t[cc][rr]);
    }
}

// ---------- K2: channel MLP:  ch = sigmoid(relu(m@W1+b1)@W2+b2) ----------
__global__ __launch_bounds__(256) void ch_kernel(const float* __restrict__ part,
                                                 const float* __restrict__ w1,
                                                 const float* __restrict__ b1,
                                                 const float* __restrict__ w2,
                                                 const float* __restrict__ b2,
                                                 float* __restrict__ ch) {
    int b = blockIdx.x, tid = threadIdx.x;
    __shared__ float mrow[1024];
    __shared__ float hid[256];
    for (int i = tid; i < 1024; i += 256) {
        float s = 0.f;
        for (int j = 0; j < 64; j++) s += part[((size_t)b * 64 + j) * 1024 + i];
        mrow[i] = s * (1.f / 2048.f);
    }
    __syncthreads();
    {
        float s = 0.f;
        for (int i = 0; i < 1024; i++) s += mrow[i] * w1[(size_t)i * 256 + tid];
        hid[tid] = fmaxf(s + b1[tid], 0.f);
    }
    __syncthreads();
    for (int c = tid; c < 1024; c += 256) {
        float s = 0.f;
        for (int j = 0; j < 256; j++) s += hid[j] * w2[(size_t)j * 1024 + c];
        ch[(size_t)b * 1024 + c] = 1.f / (1.f + expf(-(s + b2[c])));
    }
}

// ---------- K3: qkv GEMM, fused stats (q/k blocks) + compact scaled v (v blocks) ----------
// C columns: 0..2047 interleaved q/k (col 2j = q_j, col 2j+1 = k_j), 2048..3071 = v.
// bn 0..15: compute 5 row-stats partials -> part2[(bn*5+f)*16384 + row].  No C write.
// bn 16..23: write v*ch (bf16) to vbuf[16384][1024] via LDS-coalesced short8 stores.
__global__ __launch_bounds__(256) void gemm_qkv_kernel(const short* __restrict__ A,   // [16384][1024]
                                                       const short* __restrict__ BT,  // [3072][1024]
                                                       short* __restrict__ vbuf,      // [16384][1024]
                                                       const float* __restrict__ ch,  // [8][1024]
                                                       float* __restrict__ part2)     // [16*5][16384]
{
    __shared__ __align__(16) short Ash[2 * 128 * 32];
    __shared__ __align__(16) short Bsh[2 * 128 * 32];
    const int tid = threadIdx.x;
    const int wave = tid >> 6, lane = tid & 63;
    const int id = blockIdx.x;
    const int xcd = id & 7, j = id >> 3;          // j in 0..383 per XCD walk
    const int half = j / 192;                     // bm group of 8
    const int rem = j % 192;
    const int bmi = rem & 7;
    const int bn = rem >> 3;                      // 0..23, changes fast -> A group stays L2-hot
    const int bm = (half * 8 + bmi) * 8 + xcd;    // 0..127
    const int wm = wave >> 1, wn = wave & 1;
    const int l4 = lane >> 2, kk = (lane & 3) * 8;
    const int lda = 1024, ldb = 1024;

    const short* Ag = A + (size_t)(bm * 128 + wave * 32 + l4) * lda + kk;
    const short* Bg = BT + (size_t)(bn * 128 + wave * 32 + l4) * ldb + kk;
    short* lA = Ash + wave * 1024;
    short* lB = Bsh + wave * 1024;

    floatx4 acc[4][4];
    floatx4 zero = {0.f, 0.f, 0.f, 0.f};
#pragma unroll
    for (int i = 0; i < 4; i++)
#pragma unroll
        for (int jj = 0; jj < 4; jj++) acc[i][jj] = zero;

    const int ar = lane & 15, ak = (lane >> 4) * 8;
    const int quad = lane >> 4;

    for (int k0 = 0; k0 < 1024; k0 += 64) {
#pragma unroll
        for (int h = 0; h < 2; h++) {
            gl_lds16(Ag + k0 + h * 32, lA + h * 4096);
            gl_lds16(Ag + 16 * lda + k0 + h * 32, lA + h * 4096 + 512);
            gl_lds16(Bg + k0 + h * 32, lB + h * 4096);
            gl_lds16(Bg + 16 * ldb + k0 + h * 32, lB + h * 4096 + 512);
        }
        __syncthreads();
#pragma unroll
        for (int h = 0; h < 2; h++) {
            short8 af[4], bfr[4];
#pragma unroll
            for (int t = 0; t < 4; t++)
                af[t] = *(const short8*)(Ash + h * 4096 + (wm * 64 + t * 16 + ar) * 32 + ak);
#pragma unroll
            for (int t = 0; t < 4; t++)
                bfr[t] = *(const short8*)(Bsh + h * 4096 + (wn * 64 + t * 16 + ar) * 32 + ak);
#pragma unroll
            for (int i = 0; i < 4; i++)
#pragma unroll
                for (int jj = 0; jj < 4; jj++)
                    acc[i][jj] = __builtin_amdgcn_mfma_f32_16x16x32_bf16(af[i], bfr[jj], acc[i][jj], 0, 0, 0);
        }
        __syncthreads();
    }
    // K-loop ended with __syncthreads -> LDS reusable.

    if (bn < 16) {
        // ---- fused q/k stats ----
        float* sb = (float*)Ash;   // [2 wn][128 rows][5] = 5 KB
#pragma unroll
        for (int i = 0; i < 4; i++) {
            float st[4][5];
#pragma unroll
            for (int r = 0; r < 4; r++)
#pragma unroll
                for (int f = 0; f < 5; f++) st[r][f] = 0.f;
#pragma unroll
            for (int jj = 0; jj < 4; jj++) {
#pragma unroll
                for (int r = 0; r < 4; r++) {
                    float val = acc[i][jj][r];
                    float other = __shfl_xor(val, 1);
                    float q = (lane & 1) ? other : val;
                    float kv = (lane & 1) ? val : other;
                    st[r][0] += q; st[r][1] += kv;
                    st[r][2] += q * q; st[r][3] += kv * kv; st[r][4] += q * kv;
                }
            }
            // reduce the 8 same-parity lanes of each 16-lane row group
#pragma unroll
            for (int r = 0; r < 4; r++)
#pragma unroll
                for (int f = 0; f < 5; f++) {
                    float v = st[r][f];
                    v += __shfl_xor(v, 2);
                    v += __shfl_xor(v, 4);
                    v += __shfl_xor(v, 8);
                    st[r][f] = v;
                }
            if ((lane & 15) == 0) {
#pragma unroll
                for (int r = 0; r < 4; r++)
#pragma unroll
                    for (int f = 0; f < 5; f++)
                        sb[(size_t)(wn * 128 + wm * 64 + i * 16 + quad * 4 + r) * 5 + f] = st[r][f];
            }
        }
        __syncthreads();
        if (tid < 128) {
            int grow = bm * 128 + tid;
#pragma unroll
            for (int f = 0; f < 5; f++) {
                float s = sb[(size_t)tid * 5 + f] + sb[(size_t)(128 + tid) * 5 + f];
                part2[(size_t)(bn * 5 + f) * 16384 + grow] = s;
            }
        }
    } else {
        // ---- v*ch, LDS repack -> coalesced short8 stores ----
        const int batch = (bm * 128) >> 11;
        const int vcol0 = bn * 128 - 2048 + wn * 64;
        short* pbuf = Ash + wave * 1024;   // [16 rows][64 cols] bf16, per-wave slice
        float cw[4];
#pragma unroll
        for (int jj = 0; jj < 4; jj++) cw[jj] = ch[(size_t)batch * 1024 + vcol0 + jj * 16 + ar];
#pragma unroll
        for (int i = 0; i < 4; i++) {
#pragma unroll
            for (int jj = 0; jj < 4; jj++)
#pragma unroll
                for (int r = 0; r < 4; r++)
                    pbuf[(quad * 4 + r) * 64 + jj * 16 + ar] = (short)f2bf(acc[i][jj][r] * cw[jj]);
#pragma unroll
            for (int p = 0; p < 2; p++) {
                int idx = p * 512 + lane * 8;
                short8 vv = *(const short8*)(pbuf + idx);
                int grow = bm * 128 + wm * 64 + i * 16 + (idx >> 6);
                int gcol = vcol0 + (idx & 63);
                *(short8*)(vbuf + (size_t)grow * 1024 + gcol) = vv;
            }
        }
    }
}

// ---------- K4: stats finalize -> attn_base ----------
__global__ __launch_bounds__(256) void finalize_kernel(const float* __restrict__ part2,
                                                       const float* __restrict__ c1p,
                                                       const float* __restrict__ c2p,
                                                       float* __restrict__ attn) {
    int row = blockIdx.x * 256 + threadIdx.x;
    float s[5] = {0.f, 0.f, 0.f, 0.f, 0.f};
#pragma unroll
    for (int slot = 0; slot < 16; slot++)
#pragma unroll
        for (int f = 0; f < 5; f++)
            s[f] += part2[(size_t)((slot * 5 + f) << 14) + row];
    const float C = 1024.f, invcm1 = 1.f / 1023.f;
    float c1 = *c1p, c2 = *c2p;
    float muq = s[0] / C, muk = s[1] / C;
    float sigqk = (s[4] - C * muq * muk) * invcm1;
    float sigq2 = (s[2] - C * muq * muq) * invcm1;
    float sigk2 = (s[3] - C * muk * muk) * invcm1;
    float num = (2.f * muq * muk + c1) * (2.f * sigqk + c2);
    float den = (muq * muq + muk * muk + c1) * (sigq2 + sigk2 + c2);
    float r = num / (den + 1e-7f);
    attn[row] = r * r;
}

// ---------- block reduce helpers ----------
__device__ __forceinline__ float blk_sum(float v, float* buf) {
#pragma unroll
    for (int m = 1; m < 64; m <<= 1) v += __shfl_xor(v, m);
    int wave = threadIdx.x >> 6;
    if ((threadIdx.x & 63) == 0) buf[wave] = v;
    __syncthreads();
    float r = buf[0] + buf[1] + buf[2] + buf[3];
    __syncthreads();
    return r;
}
__device__ __forceinline__ float blk_max(float v, float* buf) {
#pragma unroll
    for (int m = 1; m < 64; m <<= 1) v = fmaxf(v, __shfl_xor(v, m));
    int wave = threadIdx.x >> 6;
    if ((threadIdx.x & 63) == 0) buf[wave] = v;
    __syncthreads();
    float r = fmaxf(fmaxf(buf[0], buf[1]), fmaxf(buf[2], buf[3]));
    __syncthreads();
    return r;
}

// ---------- K5: ODE step (conv1->GN->relu->conv2) + sigmoid + softmax ----------
__global__ __launch_bounds__(256) void ode_softmax_kernel(const float* __restrict__ attn,
                                                          const float* __restrict__ w1,
                                                          const float* __restrict__ gng,
                                                          const float* __restrict__ gnb,
                                                          const float* __restrict__ w2,
                                                          const float* __restrict__ b2,
                                                          float* __restrict__ wgt) {
    int b = blockIdx.x, tid = threadIdx.x;
    __shared__ float A0[2048];
    __shared__ float H[4][2048];
    __shared__ float rbuf[4];
    for (int i = tid; i < 2048; i += 256) A0[i] = attn[(size_t)b * 2048 + i];
    __syncthreads();
    float w1l[12], w2l[12];
#pragma unroll
    for (int i = 0; i < 12; i++) { w1l[i] = w1[i]; w2l[i] = w2[i]; }
    float gg[4], gb[4];
#pragma unroll
    for (int c = 0; c < 4; c++) { gg[c] = gng[c]; gb[c] = gnb[c]; }

    float s0 = 0.f, ss0 = 0.f, s1 = 0.f, ss1 = 0.f;
    for (int i = tid; i < 2048; i += 256) {
        float le = (i > 0) ? A0[i - 1] : 0.f;
        float mi = A0[i];
        float ri = (i < 2047) ? A0[i + 1] : 0.f;
#pragma unroll
        for (int c = 0; c < 4; c++) {
            float h = w1l[c * 3] * le + w1l[c * 3 + 1] * mi + w1l[c * 3 + 2] * ri;
            H[c][i] = h;
            if (c < 2) { s0 += h; ss0 += h * h; } else { s1 += h; ss1 += h * h; }
        }
    }
    s0 = blk_sum(s0, rbuf);
    ss0 = blk_sum(ss0, rbuf);
    s1 = blk_sum(s1, rbuf);
    ss1 = blk_sum(ss1, rbuf);
    float mu0 = s0 / 4096.f, var0 = ss0 / 4096.f - mu0 * mu0;
    float mu1 = s1 / 4096.f, var1 = ss1 / 4096.f - mu1 * mu1;
    float is0 = 1.f / sqrtf(var0 + 1e-5f);
    float is1 = 1.f / sqrtf(var1 + 1e-5f);

    for (int i = tid; i < 2048; i += 256) {
#pragma unroll
        for (int c = 0; c < 4; c++) {
            float inv = (c < 2) ? is0 : is1;
            float mu = (c < 2) ? mu0 : mu1;
            float v = (H[c][i] - mu) * inv * gg[c] + gb[c];
            H[c][i] = fmaxf(v, 0.f);
        }
    }
    __syncthreads();

    float bias2 = b2[0];
    float myfa[8];
    float lmax = -1e30f;
#pragma unroll
    for (int ii = 0; ii < 8; ii++) {
        int i = tid + ii * 256;
        float y = bias2;
#pragma unroll
        for (int c = 0; c < 4; c++) {
            float le = (i > 0) ? H[c][i - 1] : 0.f;
            float mi = H[c][i];
            float ri = (i < 2047) ? H[c][i + 1] : 0.f;
            y += w2l[c * 3] * le + w2l[c * 3 + 1] * mi + w2l[c * 3 + 2] * ri;
        }
        float Av = A0[i] + y;
        float fa = 1.f / (1.f + expf(-Av));
        myfa[ii] = fa;
        lmax = fmaxf(lmax, fa);
    }
    float gmax = blk_max(lmax, rbuf);
    float lsum = 0.f;
#pragma unroll
    for (int ii = 0; ii < 8; ii++) {
        myfa[ii] = expf(myfa[ii] - gmax);
        lsum += myfa[ii];
    }
    float gsum = blk_sum(lsum, rbuf);
    float inv = 1.f / gsum;
#pragma unroll
    for (int ii = 0; ii < 8; ii++) wgt[(size_t)b * 2048 + tid + ii * 256] = myfa[ii] * inv;
}

// ---------- K6: out GEMM: out = w[row]*(vbuf @ projT) + proj_b, LDS-coalesced f32 stores ----------
__global__ __launch_bounds__(256) void gemm_out_kernel(const short* __restrict__ vbuf,  // [16384][1024]
                                                       const short* __restrict__ BT,    // projT [1024][1024]
                                                       const float* __restrict__ wgt,   // [16384]
                                                       const float* __restrict__ pb,    // [1024]
                                                       float* __restrict__ Out)         // [16384][1024]
{
    __shared__ __align__(16) short Ash[2 * 128 * 32];
    __shared__ __align__(16) short Bsh[2 * 128 * 32];
    const int tid = threadIdx.x;
    const int wave = tid >> 6, lane = tid & 63;
    const int id = blockIdx.x;
    const int xcd = id & 7, j = id >> 3;        // 0..127
    const int half = j >> 6;
    const int rem = j & 63;
    const int bmi = rem & 7;
    const int bn = rem >> 3;                    // 0..7
    const int bm = (half * 8 + bmi) * 8 + xcd;  // 0..127
    const int wm = wave >> 1, wn = wave & 1;
    const int l4 = lane >> 2, kk = (lane & 3) * 8;
    const int lda = 1024, ldb = 1024;

    const short* Ag = vbuf + (size_t)(bm * 128 + wave * 32 + l4) * lda + kk;
    const short* Bg = BT + (size_t)(bn * 128 + wave * 32 + l4) * ldb + kk;
    short* lA = Ash + wave * 1024;
    short* lB = Bsh + wave * 1024;

    floatx4 acc[4][4];
    floatx4 zero = {0.f, 0.f, 0.f, 0.f};
#pragma unroll
    for (int i = 0; i < 4; i++)
#pragma unroll
        for (int jj = 0; jj < 4; jj++) acc[i][jj] = zero;

    const int ar = lane & 15, ak = (lane >> 4) * 8;
    const int quad = lane >> 4;

    for (int k0 = 0; k0 < 1024; k0 += 64) {
#pragma unroll
        for (int h = 0; h < 2; h++) {
            gl_lds16(Ag + k0 + h * 32, lA + h * 4096);
            gl_lds16(Ag + 16 * lda + k0 + h * 32, lA + h * 4096 + 512);
            gl_lds16(Bg + k0 + h * 32, lB + h * 4096);
            gl_lds16(Bg + 16 * ldb + k0 + h * 32, lB + h * 4096 + 512);
        }
        __syncthreads();
#pragma unroll
        for (int h = 0; h < 2; h++) {
            short8 af[4], bfr[4];
#pragma unroll
            for (int t = 0; t < 4; t++)
                af[t] = *(const short8*)(Ash + h * 4096 + (wm * 64 + t * 16 + ar) * 32 + ak);
#pragma unroll
            for (int t = 0; t < 4; t++)
                bfr[t] = *(const short8*)(Bsh + h * 4096 + (wn * 64 + t * 16 + ar) * 32 + ak);
#pragma unroll
            for (int i = 0; i < 4; i++)
#pragma unroll
                for (int jj = 0; jj < 4; jj++)
                    acc[i][jj] = __builtin_amdgcn_mfma_f32_16x16x32_bf16(af[i], bfr[jj], acc[i][jj], 0, 0, 0);
        }
        __syncthreads();
    }

    const int row0 = bm * 128 + wm * 64;
    const int col0 = bn * 128 + wn * 64;
    float* obuf = (float*)Ash + wave * 1024;   // [16 rows][64 cols] fp32 per wave
#pragma unroll
    for (int i = 0; i < 4; i++) {
#pragma unroll
        for (int jj = 0; jj < 4; jj++) {
            float bias = pb[col0 + jj * 16 + ar];
#pragma unroll
            for (int r = 0; r < 4; r++) {
                int grow = row0 + i * 16 + quad * 4 + r;
                obuf[(quad * 4 + r) * 64 + jj * 16 + ar] = wgt[grow] * acc[i][jj][r] + bias;
            }
        }
#pragma unroll
        for (int p = 0; p < 4; p++) {
            int idx = p * 256 + lane * 4;
            float4 vv = *(const float4*)(obuf + idx);
            int grow = row0 + i * 16 + (idx >> 6);
            int gcol = col0 + (idx & 63);
            *(float4*)(Out + (size_t)grow * 1024 + gcol) = vv;
        }
    }
}

extern "C" void kernel_launch(void* const* d_in, const int* in_sizes, int n_in,
                              void* d_out, int out_size, void* d_ws, size_t ws_size,
                              hipStream_t stream) {
    const float* x       = (const float*)d_in[0];
    const float* qkv_w   = (const float*)d_in[1];
    const float* c1      = (const float*)d_in[2];
    const float* c2      = (const float*)d_in[3];
    const float* conv1_w = (const float*)d_in[4];
    const float* gn_g    = (const float*)d_in[5];
    const float* gn_b    = (const float*)d_in[6];
    const float* conv2_w = (const float*)d_in[7];
    const float* conv2_b = (const float*)d_in[8];
    const float* ch_w1   = (const float*)d_in[9];
    const float* ch_b1   = (const float*)d_in[10];
    const float* ch_w2   = (const float*)d_in[11];
    const float* ch_b2   = (const float*)d_in[12];
    const float* proj_w  = (const float*)d_in[13];
    const float* proj_b  = (const float*)d_in[14];
    float* out = (float*)d_out;

    size_t off = 0;
    char* base = (char*)d_ws;
    auto carve = [&](size_t bytes) -> char* {
        char* p = base + off;
        off += (bytes + 255) & ~(size_t)255;
        return p;
    };
    short* x_bf  = (short*)carve((size_t)16384 * 1024 * 2);   // 33.6 MB
    short* qkvT  = (short*)carve((size_t)3072 * 1024 * 2);    // 6.3 MB
    short* projT = (short*)carve((size_t)1024 * 1024 * 2);    // 2.1 MB
    short* vbuf  = (short*)carve((size_t)16384 * 1024 * 2);   // 33.6 MB
    float* part2 = (float*)carve((size_t)80 * 16384 * 4);     // 5.2 MB
    float* attn  = (float*)carve((size_t)16384 * 4);
    float* wgt   = (float*)carve((size_t)16384 * 4);
    float* part  = (float*)carve((size_t)8 * 64 * 1024 * 4);
    float* chw   = (float*)carve((size_t)8 * 1024 * 4);

    convmean_kernel<<<512, 256, 0, stream>>>(x, x_bf, part);
    transpose_conv_kernel<<<dim3(64, 16), 256, 0, stream>>>(qkv_w, qkvT, proj_w, projT);
    ch_kernel<<<8, 256, 0, stream>>>(part, ch_w1, ch_b1, ch_w2, ch_b2, chw);
    gemm_qkv_kernel<<<3072, 256, 0, stream>>>(x_bf, qkvT, vbuf, chw, part2);
    finalize_kernel<<<64, 256, 0, stream>>>(part2, c1, c2, attn);
    ode_softmax_kernel<<<8, 256, 0, stream>>>(attn, conv1_w, gn_g, gn_b, conv2_w, conv2_b, wgt);
    gemm_out_kernel<<<1024, 256, 0, stream>>>(vbuf, projT, wgt, proj_b, out);
}

// Round 4
// 387.338 us; speedup vs baseline: 1.3924x; 1.3924x over previous
//
#include <hip/hip_runtime.h>

typedef __attribute__((ext_vector_type(8))) short short8;
typedef __attribute__((ext_vector_type(4))) short short4v;
typedef __attribute__((ext_vector_type(4))) float floatx4;

// ---------- bf16 helpers (manual, RNE) ----------
__device__ __forceinline__ unsigned short f2bf(float f) {
    unsigned u = __float_as_uint(f);
    u = u + 0x7fffu + ((u >> 16) & 1u);
    return (unsigned short)(u >> 16);
}
__device__ __forceinline__ float bf2f(short s) {
    return __uint_as_float(((unsigned)(unsigned short)s) << 16);
}

// ---------- async global->LDS, 16B per lane ----------
__device__ __forceinline__ void gl_lds16(const void* g, void* l) {
    __builtin_amdgcn_global_load_lds((const __attribute__((address_space(1))) void*)g,
                                     (__attribute__((address_space(3))) void*)l, 16, 0, 0);
}

// ---------- K0: fused convert x->bf16 + partial column sums over N ----------
__global__ __launch_bounds__(256) void convmean_kernel(const float* __restrict__ x,
                                                       short* __restrict__ xb,
                                                       float* __restrict__ part) {
    int bid = blockIdx.x;
    int b = bid >> 6, nch = bid & 63;
    int tid = threadIdx.x;
    size_t base = ((size_t)b * 2048 + nch * 32) * 1024;
    float s0 = 0.f, s1 = 0.f, s2 = 0.f, s3 = 0.f;
    int c0 = tid * 4;
    for (int r = 0; r < 32; r++) {
        const float* rp = x + base + (size_t)r * 1024 + c0;
        float4 v = *(const float4*)rp;
        s0 += v.x; s1 += v.y; s2 += v.z; s3 += v.w;
        short4v o;
        o[0] = (short)f2bf(v.x); o[1] = (short)f2bf(v.y);
        o[2] = (short)f2bf(v.z); o[3] = (short)f2bf(v.w);
        *(short4v*)(xb + base + (size_t)r * 1024 + c0) = o;
    }
    float* pp = part + ((size_t)b * 64 + nch) * 1024 + c0;
    float4 ps; ps.x = s0; ps.y = s1; ps.z = s2; ps.w = s3;
    *(float4*)pp = ps;
}

// ---------- K1: fused transpose+convert, with q/k interleave permutation ----------
// qkvT row for original qkv_w column j:  q_j -> 2j,  k_j -> 2j+1,  v_j -> unchanged
__global__ __launch_bounds__(256) void transpose_conv_kernel(const float* __restrict__ w_qkv,
                                                             short* __restrict__ qkvT,
                                                             const float* __restrict__ w_proj,
                                                             short* __restrict__ projT) {
    __shared__ float t[64][65];
    int bx = blockIdx.x;
    const float* in; short* out; int C; bool is_qkv;
    int c0, r0 = blockIdx.y * 64;
    if (bx < 48) { in = w_qkv; out = qkvT; C = 3072; c0 = bx * 64; is_qkv = true; }
    else         { in = w_proj; out = projT; C = 1024; c0 = (bx - 48) * 64; is_qkv = false; }
    int tid = threadIdx.x;
#pragma unroll
    for (int l = 0; l < 16; l++) {
        int idx = l * 256 + tid;
        int rr = idx >> 6, cc = idx & 63;
        t[rr][cc] = in[(size_t)(r0 + rr) * C + c0 + cc];
    }
    __syncthreads();
#pragma unroll
    for (int l = 0; l < 16; l++) {
        int idx = l * 256 + tid;
        int rr = idx >> 6, cc = idx & 63;
        int ro = c0 + rr;
        int rnew = ro;
        if (is_qkv) {
            if (ro < 1024) rnew = 2 * ro;
            else if (ro < 2048) rnew = 2 * (ro - 1024) + 1;
        }
        out[(size_t)rnew * 1024 + r0 + cc] = (short)f2bf(t[cc][rr]);
    }
}

// ---------- K2: channel MLP, 64 blocks (8 batch x 8 col-groups) ----------
__global__ __launch_bounds__(256) void ch_kernel(const float* __restrict__ part,
                                                 const float* __restrict__ w1,
                                                 const float* __restrict__ b1,
                                                 const float* __restrict__ w2,
                                                 const float* __restrict__ b2,
                                                 float* __restrict__ ch) {
    int b = blockIdx.x >> 3, cg = blockIdx.x & 7;
    int tid = threadIdx.x;
    __shared__ float mrow[1024];
    __shared__ float hid[256];
    for (int i = tid; i < 1024; i += 256) {
        float s = 0.f;
        for (int j = 0; j < 64; j++) s += part[((size_t)b * 64 + j) * 1024 + i];
        mrow[i] = s * (1.f / 2048.f);
    }
    __syncthreads();
    {
        float s0 = 0.f, s1 = 0.f, s2 = 0.f, s3 = 0.f;
        for (int i = 0; i < 1024; i += 4) {
            s0 += mrow[i] * w1[(size_t)i * 256 + tid];
            s1 += mrow[i + 1] * w1[(size_t)(i + 1) * 256 + tid];
            s2 += mrow[i + 2] * w1[(size_t)(i + 2) * 256 + tid];
            s3 += mrow[i + 3] * w1[(size_t)(i + 3) * 256 + tid];
        }
        hid[tid] = fmaxf((s0 + s1) + (s2 + s3) + b1[tid], 0.f);
    }
    __syncthreads();
    if (tid < 128) {
        int c = cg * 128 + tid;
        float s0 = 0.f, s1 = 0.f, s2 = 0.f, s3 = 0.f;
        for (int j = 0; j < 256; j += 4) {
            s0 += hid[j] * w2[(size_t)j * 1024 + c];
            s1 += hid[j + 1] * w2[(size_t)(j + 1) * 1024 + c];
            s2 += hid[j + 2] * w2[(size_t)(j + 2) * 1024 + c];
            s3 += hid[j + 3] * w2[(size_t)(j + 3) * 1024 + c];
        }
        float s = (s0 + s1) + (s2 + s3) + b2[c];
        ch[(size_t)b * 1024 + c] = 1.f / (1.f + expf(-s));
    }
}

// ---------- K3: qkv GEMM, fused stats (q/k blocks) + compact scaled v (v blocks) ----------
// __launch_bounds__(256,4): cap VGPR at 128 — round 3's 136-VGPR epilogue halved occupancy.
__global__ __launch_bounds__(256, 4) void gemm_qkv_kernel(const short* __restrict__ A,   // [16384][1024]
                                                          const short* __restrict__ BT,  // [3072][1024]
                                                          short* __restrict__ vbuf,      // [16384][1024]
                                                          const float* __restrict__ ch,  // [8][1024]
                                                          float* __restrict__ part2)     // [16*5][16384]
{
    __shared__ __align__(16) short Ash[2 * 128 * 32];
    __shared__ __align__(16) short Bsh[2 * 128 * 32];
    const int tid = threadIdx.x;
    const int wave = tid >> 6, lane = tid & 63;
    const int id = blockIdx.x;
    const int xcd = id & 7, j = id >> 3;          // j in 0..383 per XCD walk
    const int half = j / 192;                     // bm group of 8
    const int rem = j % 192;
    const int bmi = rem & 7;
    const int bn = rem >> 3;                      // 0..23, changes fast -> A group stays L2-hot
    const int bm = (half * 8 + bmi) * 8 + xcd;    // 0..127
    const int wm = wave >> 1, wn = wave & 1;
    const int l4 = lane >> 2, kk = (lane & 3) * 8;
    const int lda = 1024, ldb = 1024;

    const short* Ag = A + (size_t)(bm * 128 + wave * 32 + l4) * lda + kk;
    const short* Bg = BT + (size_t)(bn * 128 + wave * 32 + l4) * ldb + kk;
    short* lA = Ash + wave * 1024;
    short* lB = Bsh + wave * 1024;

    floatx4 acc[4][4];
    floatx4 zero = {0.f, 0.f, 0.f, 0.f};
#pragma unroll
    for (int i = 0; i < 4; i++)
#pragma unroll
        for (int jj = 0; jj < 4; jj++) acc[i][jj] = zero;

    const int ar = lane & 15, ak = (lane >> 4) * 8;
    const int quad = lane >> 4;

    for (int k0 = 0; k0 < 1024; k0 += 64) {
#pragma unroll
        for (int h = 0; h < 2; h++) {
            gl_lds16(Ag + k0 + h * 32, lA + h * 4096);
            gl_lds16(Ag + 16 * lda + k0 + h * 32, lA + h * 4096 + 512);
            gl_lds16(Bg + k0 + h * 32, lB + h * 4096);
            gl_lds16(Bg + 16 * ldb + k0 + h * 32, lB + h * 4096 + 512);
        }
        __syncthreads();
#pragma unroll
        for (int h = 0; h < 2; h++) {
            short8 af[4], bfr[4];
#pragma unroll
            for (int t = 0; t < 4; t++)
                af[t] = *(const short8*)(Ash + h * 4096 + (wm * 64 + t * 16 + ar) * 32 + ak);
#pragma unroll
            for (int t = 0; t < 4; t++)
                bfr[t] = *(const short8*)(Bsh + h * 4096 + (wn * 64 + t * 16 + ar) * 32 + ak);
#pragma unroll
            for (int i = 0; i < 4; i++)
#pragma unroll
                for (int jj = 0; jj < 4; jj++)
                    acc[i][jj] = __builtin_amdgcn_mfma_f32_16x16x32_bf16(af[i], bfr[jj], acc[i][jj], 0, 0, 0);
        }
        __syncthreads();
    }
    // K-loop ended with __syncthreads -> LDS reusable.

    if (bn < 16) {
        // ---- fused q/k stats ----
        float* sb = (float*)Ash;   // [2 wn][128 rows][5] = 5 KB
#pragma unroll
        for (int i = 0; i < 4; i++) {
            float st[4][5];
#pragma unroll
            for (int r = 0; r < 4; r++)
#pragma unroll
                for (int f = 0; f < 5; f++) st[r][f] = 0.f;
#pragma unroll
            for (int jj = 0; jj < 4; jj++) {
#pragma unroll
                for (int r = 0; r < 4; r++) {
                    float val = acc[i][jj][r];
                    float other = __shfl_xor(val, 1);
                    float q = (lane & 1) ? other : val;
                    float kv = (lane & 1) ? val : other;
                    st[r][0] += q; st[r][1] += kv;
                    st[r][2] += q * q; st[r][3] += kv * kv; st[r][4] += q * kv;
                }
            }
#pragma unroll
            for (int r = 0; r < 4; r++)
#pragma unroll
                for (int f = 0; f < 5; f++) {
                    float v = st[r][f];
                    v += __shfl_xor(v, 2);
                    v += __shfl_xor(v, 4);
                    v += __shfl_xor(v, 8);
                    st[r][f] = v;
                }
            if ((lane & 15) == 0) {
#pragma unroll
                for (int r = 0; r < 4; r++)
#pragma unroll
                    for (int f = 0; f < 5; f++)
                        sb[(size_t)(wn * 128 + wm * 64 + i * 16 + quad * 4 + r) * 5 + f] = st[r][f];
            }
        }
        __syncthreads();
        if (tid < 128) {
            int grow = bm * 128 + tid;
#pragma unroll
            for (int f = 0; f < 5; f++) {
                float s = sb[(size_t)tid * 5 + f] + sb[(size_t)(128 + tid) * 5 + f];
                part2[(size_t)(bn * 5 + f) * 16384 + grow] = s;
            }
        }
    } else {
        // ---- v*ch, LDS repack -> coalesced short8 stores ----
        const int batch = (bm * 128) >> 11;
        const int vcol0 = bn * 128 - 2048 + wn * 64;
        short* pbuf = Ash + wave * 1024;   // [16 rows][64 cols] bf16, per-wave slice
        float cw[4];
#pragma unroll
        for (int jj = 0; jj < 4; jj++) cw[jj] = ch[(size_t)batch * 1024 + vcol0 + jj * 16 + ar];
#pragma unroll
        for (int i = 0; i < 4; i++) {
#pragma unroll
            for (int jj = 0; jj < 4; jj++)
#pragma unroll
                for (int r = 0; r < 4; r++)
                    pbuf[(quad * 4 + r) * 64 + jj * 16 + ar] = (short)f2bf(acc[i][jj][r] * cw[jj]);
#pragma unroll
            for (int p = 0; p < 2; p++) {
                int idx = p * 512 + lane * 8;
                short8 vv = *(const short8*)(pbuf + idx);
                int grow = bm * 128 + wm * 64 + i * 16 + (idx >> 6);
                int gcol = vcol0 + (idx & 63);
                *(short8*)(vbuf + (size_t)grow * 1024 + gcol) = vv;
            }
        }
    }
}

// ---------- K4: stats finalize -> attn_base ----------
__global__ __launch_bounds__(256) void finalize_kernel(const float* __restrict__ part2,
                                                       const float* __restrict__ c1p,
                                                       const float* __restrict__ c2p,
                                                       float* __restrict__ attn) {
    int row = blockIdx.x * 256 + threadIdx.x;
    float s[5] = {0.f, 0.f, 0.f, 0.f, 0.f};
#pragma unroll
    for (int slot = 0; slot < 16; slot++)
#pragma unroll
        for (int f = 0; f < 5; f++)
            s[f] += part2[(size_t)((slot * 5 + f) << 14) + row];
    const float C = 1024.f, invcm1 = 1.f / 1023.f;
    float c1 = *c1p, c2 = *c2p;
    float muq = s[0] / C, muk = s[1] / C;
    float sigqk = (s[4] - C * muq * muk) * invcm1;
    float sigq2 = (s[2] - C * muq * muq) * invcm1;
    float sigk2 = (s[3] - C * muk * muk) * invcm1;
    float num = (2.f * muq * muk + c1) * (2.f * sigqk + c2);
    float den = (muq * muq + muk * muk + c1) * (sigq2 + sigk2 + c2);
    float r = num / (den + 1e-7f);
    attn[row] = r * r;
}

// ---------- block reduce helpers ----------
__device__ __forceinline__ float blk_sum(float v, float* buf) {
#pragma unroll
    for (int m = 1; m < 64; m <<= 1) v += __shfl_xor(v, m);
    int wave = threadIdx.x >> 6;
    if ((threadIdx.x & 63) == 0) buf[wave] = v;
    __syncthreads();
    float r = buf[0] + buf[1] + buf[2] + buf[3];
    __syncthreads();
    return r;
}
__device__ __forceinline__ float blk_max(float v, float* buf) {
#pragma unroll
    for (int m = 1; m < 64; m <<= 1) v = fmaxf(v, __shfl_xor(v, m));
    int wave = threadIdx.x >> 6;
    if ((threadIdx.x & 63) == 0) buf[wave] = v;
    __syncthreads();
    float r = fmaxf(fmaxf(buf[0], buf[1]), fmaxf(buf[2], buf[3]));
    __syncthreads();
    return r;
}

// ---------- K5: ODE step (conv1->GN->relu->conv2) + sigmoid + softmax ----------
__global__ __launch_bounds__(256) void ode_softmax_kernel(const float* __restrict__ attn,
                                                          const float* __restrict__ w1,
                                                          const float* __restrict__ gng,
                                                          const float* __restrict__ gnb,
                                                          const float* __restrict__ w2,
                                                          const float* __restrict__ b2,
                                                          float* __restrict__ wgt) {
    int b = blockIdx.x, tid = threadIdx.x;
    __shared__ float A0[2048];
    __shared__ float H[4][2048];
    __shared__ float rbuf[4];
    for (int i = tid; i < 2048; i += 256) A0[i] = attn[(size_t)b * 2048 + i];
    __syncthreads();
    float w1l[12], w2l[12];
#pragma unroll
    for (int i = 0; i < 12; i++) { w1l[i] = w1[i]; w2l[i] = w2[i]; }
    float gg[4], gb[4];
#pragma unroll
    for (int c = 0; c < 4; c++) { gg[c] = gng[c]; gb[c] = gnb[c]; }

    float s0 = 0.f, ss0 = 0.f, s1 = 0.f, ss1 = 0.f;
    for (int i = tid; i < 2048; i += 256) {
        float le = (i > 0) ? A0[i - 1] : 0.f;
        float mi = A0[i];
        float ri = (i < 2047) ? A0[i + 1] : 0.f;
#pragma unroll
        for (int c = 0; c < 4; c++) {
            float h = w1l[c * 3] * le + w1l[c * 3 + 1] * mi + w1l[c * 3 + 2] * ri;
            H[c][i] = h;
            if (c < 2) { s0 += h; ss0 += h * h; } else { s1 += h; ss1 += h * h; }
        }
    }
    s0 = blk_sum(s0, rbuf);
    ss0 = blk_sum(ss0, rbuf);
    s1 = blk_sum(s1, rbuf);
    ss1 = blk_sum(ss1, rbuf);
    float mu0 = s0 / 4096.f, var0 = ss0 / 4096.f - mu0 * mu0;
    float mu1 = s1 / 4096.f, var1 = ss1 / 4096.f - mu1 * mu1;
    float is0 = 1.f / sqrtf(var0 + 1e-5f);
    float is1 = 1.f / sqrtf(var1 + 1e-5f);

    for (int i = tid; i < 2048; i += 256) {
#pragma unroll
        for (int c = 0; c < 4; c++) {
            float inv = (c < 2) ? is0 : is1;
            float mu = (c < 2) ? mu0 : mu1;
            float v = (H[c][i] - mu) * inv * gg[c] + gb[c];
            H[c][i] = fmaxf(v, 0.f);
        }
    }
    __syncthreads();

    float bias2 = b2[0];
    float myfa[8];
    float lmax = -1e30f;
#pragma unroll
    for (int ii = 0; ii < 8; ii++) {
        int i = tid + ii * 256;
        float y = bias2;
#pragma unroll
        for (int c = 0; c < 4; c++) {
            float le = (i > 0) ? H[c][i - 1] : 0.f;
            float mi = H[c][i];
            float ri = (i < 2047) ? H[c][i + 1] : 0.f;
            y += w2l[c * 3] * le + w2l[c * 3 + 1] * mi + w2l[c * 3 + 2] * ri;
        }
        float Av = A0[i] + y;
        float fa = 1.f / (1.f + expf(-Av));
        myfa[ii] = fa;
        lmax = fmaxf(lmax, fa);
    }
    float gmax = blk_max(lmax, rbuf);
    float lsum = 0.f;
#pragma unroll
    for (int ii = 0; ii < 8; ii++) {
        myfa[ii] = expf(myfa[ii] - gmax);
        lsum += myfa[ii];
    }
    float gsum = blk_sum(lsum, rbuf);
    float inv = 1.f / gsum;
#pragma unroll
    for (int ii = 0; ii < 8; ii++) wgt[(size_t)b * 2048 + tid + ii * 256] = myfa[ii] * inv;
}

// ---------- K6: out GEMM: out = w[row]*(vbuf @ projT) + proj_b, LDS-coalesced f32 stores ----------
__global__ __launch_bounds__(256, 4) void gemm_out_kernel(const short* __restrict__ vbuf,  // [16384][1024]
                                                          const short* __restrict__ BT,    // projT [1024][1024]
                                                          const float* __restrict__ wgt,   // [16384]
                                                          const float* __restrict__ pb,    // [1024]
                                                          float* __restrict__ Out)         // [16384][1024]
{
    __shared__ __align__(16) short Ash[2 * 128 * 32];
    __shared__ __align__(16) short Bsh[2 * 128 * 32];
    const int tid = threadIdx.x;
    const int wave = tid >> 6, lane = tid & 63;
    const int id = blockIdx.x;
    const int xcd = id & 7, j = id >> 3;        // 0..127
    const int half = j >> 6;
    const int rem = j & 63;
    const int bmi = rem & 7;
    const int bn = rem >> 3;                    // 0..7
    const int bm = (half * 8 + bmi) * 8 + xcd;  // 0..127
    const int wm = wave >> 1, wn = wave & 1;
    const int l4 = lane >> 2, kk = (lane & 3) * 8;
    const int lda = 1024, ldb = 1024;

    const short* Ag = vbuf + (size_t)(bm * 128 + wave * 32 + l4) * lda + kk;
    const short* Bg = BT + (size_t)(bn * 128 + wave * 32 + l4) * ldb + kk;
    short* lA = Ash + wave * 1024;
    short* lB = Bsh + wave * 1024;

    floatx4 acc[4][4];
    floatx4 zero = {0.f, 0.f, 0.f, 0.f};
#pragma unroll
    for (int i = 0; i < 4; i++)
#pragma unroll
        for (int jj = 0; jj < 4; jj++) acc[i][jj] = zero;

    const int ar = lane & 15, ak = (lane >> 4) * 8;
    const int quad = lane >> 4;

    for (int k0 = 0; k0 < 1024; k0 += 64) {
#pragma unroll
        for (int h = 0; h < 2; h++) {
            gl_lds16(Ag + k0 + h * 32, lA + h * 4096);
            gl_lds16(Ag + 16 * lda + k0 + h * 32, lA + h * 4096 + 512);
            gl_lds16(Bg + k0 + h * 32, lB + h * 4096);
            gl_lds16(Bg + 16 * ldb + k0 + h * 32, lB + h * 4096 + 512);
        }
        __syncthreads();
#pragma unroll
        for (int h = 0; h < 2; h++) {
            short8 af[4], bfr[4];
#pragma unroll
            for (int t = 0; t < 4; t++)
                af[t] = *(const short8*)(Ash + h * 4096 + (wm * 64 + t * 16 + ar) * 32 + ak);
#pragma unroll
            for (int t = 0; t < 4; t++)
                bfr[t] = *(const short8*)(Bsh + h * 4096 + (wn * 64 + t * 16 + ar) * 32 + ak);
#pragma unroll
            for (int i = 0; i < 4; i++)
#pragma unroll
                for (int jj = 0; jj < 4; jj++)
                    acc[i][jj] = __builtin_amdgcn_mfma_f32_16x16x32_bf16(af[i], bfr[jj], acc[i][jj], 0, 0, 0);
        }
        __syncthreads();
    }

    const int row0 = bm * 128 + wm * 64;
    const int col0 = bn * 128 + wn * 64;
    float* obuf = (float*)Ash + wave * 1024;   // [16 rows][64 cols] fp32 per wave
#pragma unroll
    for (int i = 0; i < 4; i++) {
#pragma unroll
        for (int jj = 0; jj < 4; jj++) {
            float bias = pb[col0 + jj * 16 + ar];
#pragma unroll
            for (int r = 0; r < 4; r++) {
                int grow = row0 + i * 16 + quad * 4 + r;
                obuf[(quad * 4 + r) * 64 + jj * 16 + ar] = wgt[grow] * acc[i][jj][r] + bias;
            }
        }
#pragma unroll
        for (int p = 0; p < 4; p++) {
            int idx = p * 256 + lane * 4;
            float4 vv = *(const float4*)(obuf + idx);
            int grow = row0 + i * 16 + (idx >> 6);
            int gcol = col0 + (idx & 63);
            *(float4*)(Out + (size_t)grow * 1024 + gcol) = vv;
        }
    }
}

extern "C" void kernel_launch(void* const* d_in, const int* in_sizes, int n_in,
                              void* d_out, int out_size, void* d_ws, size_t ws_size,
                              hipStream_t stream) {
    const float* x       = (const float*)d_in[0];
    const float* qkv_w   = (const float*)d_in[1];
    const float* c1      = (const float*)d_in[2];
    const float* c2      = (const float*)d_in[3];
    const float* conv1_w = (const float*)d_in[4];
    const float* gn_g    = (const float*)d_in[5];
    const float* gn_b    = (const float*)d_in[6];
    const float* conv2_w = (const float*)d_in[7];
    const float* conv2_b = (const float*)d_in[8];
    const float* ch_w1   = (const float*)d_in[9];
    const float* ch_b1   = (const float*)d_in[10];
    const float* ch_w2   = (const float*)d_in[11];
    const float* ch_b2   = (const float*)d_in[12];
    const float* proj_w  = (const float*)d_in[13];
    const float* proj_b  = (const float*)d_in[14];
    float* out = (float*)d_out;

    size_t off = 0;
    char* base = (char*)d_ws;
    auto carve = [&](size_t bytes) -> char* {
        char* p = base + off;
        off += (bytes + 255) & ~(size_t)255;
        return p;
    };
    short* x_bf  = (short*)carve((size_t)16384 * 1024 * 2);   // 33.6 MB
    short* qkvT  = (short*)carve((size_t)3072 * 1024 * 2);    // 6.3 MB
    short* projT = (short*)carve((size_t)1024 * 1024 * 2);    // 2.1 MB
    short* vbuf  = (short*)carve((size_t)16384 * 1024 * 2);   // 33.6 MB
    float* part2 = (float*)carve((size_t)80 * 16384 * 4);     // 5.2 MB
    float* attn  = (float*)carve((size_t)16384 * 4);
    float* wgt   = (float*)carve((size_t)16384 * 4);
    float* part  = (float*)carve((size_t)8 * 64 * 1024 * 4);
    float* chw   = (float*)carve((size_t)8 * 1024 * 4);

    convmean_kernel<<<512, 256, 0, stream>>>(x, x_bf, part);
    transpose_conv_kernel<<<dim3(64, 16), 256, 0, stream>>>(qkv_w, qkvT, proj_w, projT);
    ch_kernel<<<64, 256, 0, stream>>>(part, ch_w1, ch_b1, ch_w2, ch_b2, chw);
    gemm_qkv_kernel<<<3072, 256, 0, stream>>>(x_bf, qkvT, vbuf, chw, part2);
    finalize_kernel<<<64, 256, 0, stream>>>(part2, c1, c2, attn);
    ode_softmax_kernel<<<8, 256, 0, stream>>>(attn, conv1_w, gn_g, gn_b, conv2_w, conv2_b, wgt);
    gemm_out_kernel<<<1024, 256, 0, stream>>>(vbuf, projT, wgt, proj_b, out);
}